// Round 3
// baseline (173.116 us; speedup 1.0000x reference)
//
#include <hip/hip_runtime.h>
#include <hip/hip_bf16.h>

// Problem shapes
#define B_SZ 64
#define T_PTS 300
#define N_SEG 299
#define VM 34            // 17*2
#define NPATH (B_SZ*VM)  // 2176
#define SIGC 120         // 3+9+27+81
#define FAN1 4080        // 34*120
#define H1 512
#define NOUT 155
#define CHUNK 5          // segments per lane (64*5=320 >= 299)
#define TT 75            // transpose t-tile (300/4)

// ---------------------------------------------------------------------------
// Absorb one linear segment with increment (d0,d1,d2) into state a1..a4.
// All indices compile-time constant -> stays in VGPRs.
// ---------------------------------------------------------------------------
__device__ __forceinline__ void sig_append(float a1[3], float a2[9], float a3[27], float a4[81],
                                           float d0, float d1, float d2) {
  float B1[3] = {d0, d1, d2};
  float Hh[3] = {0.5f * d0, 0.5f * d1, 0.5f * d2};
  float Tt[3] = {(1.0f / 3.0f) * d0, (1.0f / 3.0f) * d1, (1.0f / 3.0f) * d2};
  float Qq[3] = {0.25f * d0, 0.25f * d1, 0.25f * d2};
  float B2[9], B3[27];
#pragma unroll
  for (int i = 0; i < 3; i++)
#pragma unroll
    for (int j = 0; j < 3; j++) B2[i * 3 + j] = B1[i] * Hh[j];
#pragma unroll
  for (int e = 0; e < 27; e++) B3[e] = B2[e / 3] * Tt[e % 3];

#pragma unroll
  for (int e = 0; e < 81; e++) {
    float v = a4[e];
    v = fmaf(B3[e / 3], Qq[e % 3], v);       // + g4[e]
    v = fmaf(a3[e / 3], B1[e % 3], v);       // + a3 (x) g1
    v = fmaf(a2[e / 9], B2[e % 9], v);       // + a2 (x) g2
    v = fmaf(a1[e / 27], B3[e % 27], v);     // + a1 (x) g3
    a4[e] = v;
  }
#pragma unroll
  for (int e = 0; e < 27; e++) {
    float v = a3[e] + B3[e];
    v = fmaf(a2[e / 3], B1[e % 3], v);
    v = fmaf(a1[e / 9], B2[e % 9], v);
    a3[e] = v;
  }
#pragma unroll
  for (int e = 0; e < 9; e++) a2[e] = fmaf(a1[e / 3], B1[e % 3], a2[e] + B2[e]);
  a1[0] += d0; a1[1] += d1; a1[2] += d2;
}

// ---------------------------------------------------------------------------
// Kernel 0: transpose (B,C,T,V,M) -> (P=B*VM, T, C) contiguous paths; fused
// h = broadcast(b1) init (gemm1 accumulates atomically on top).
// ---------------------------------------------------------------------------
__global__ __launch_bounds__(256) void transpose_kernel(const float* __restrict__ inp,
                                                        float* __restrict__ tp,
                                                        const float* __restrict__ b1,
                                                        float* __restrict__ h) {
  const int b = blockIdx.x;       // 0..63
  const int tile = blockIdx.y;    // 0..3
  const int t0 = tile * TT;
  const int tid = threadIdx.x;
  __shared__ float lds[3 * TT * VM];  // 7650 floats = 30.6 KB

  const float* src = inp + (size_t)b * 3 * T_PTS * VM;
  for (int idx = tid; idx < 3 * TT * VM; idx += 256) {
    const int c = idx / (TT * VM);
    const int rem = idx - c * (TT * VM);
    lds[idx] = src[(c * T_PTS + t0) * VM + rem];
  }
  __syncthreads();

  for (int idx = tid; idx < VM * TT * 3; idx += 256) {
    const int vm = idx / (TT * 3);
    const int i = idx - vm * (TT * 3);
    const int tt = i / 3;
    const int c = i - tt * 3;
    tp[((size_t)(b * VM + vm) * T_PTS + t0 + tt) * 3 + c] = lds[(c * TT + tt) * VM + vm];
  }

  if (tile == 0) {
    for (int j = tid; j < H1; j += 256) h[b * H1 + j] = b1[j];
  }
}

// ---------------------------------------------------------------------------
// Kernel 1: signatures. One wave per path, zero LDS, zero scratch.
// Lane l absorbs segments [5l, 5l+5) (statically unrolled, masked tail),
// then a 6-level Kogge-Stone Chen combine over __shfl_down.
// ---------------------------------------------------------------------------
__global__ __launch_bounds__(256, 2) void sig_kernel(const float* __restrict__ tp,
                                                     float* __restrict__ sig) {
  const int w = threadIdx.x >> 6;
  const int lane = threadIdx.x & 63;
  const int p = blockIdx.x * 4 + w;   // 544*4 = 2176
  const int t0 = lane * CHUNK;

  // Contiguous per-lane load of 6 points (18 floats), static indices.
  // Tail-lane over-reads land in later ws regions (in-bounds, masked off).
  const float* bp = tp + (size_t)p * (T_PTS * 3) + t0 * 3;
  float pt[18];
#pragma unroll
  for (int i = 0; i < 18; i++) pt[i] = bp[i];

  // Masked increments: segment t0+s valid iff t0+s < 299. dx=0 <=> identity.
  float dd[15];
#pragma unroll
  for (int s = 0; s < CHUNK; s++) {
    const bool v = (t0 + s) < N_SEG;
#pragma unroll
    for (int c = 0; c < 3; c++)
      dd[3 * s + c] = v ? (pt[3 * s + 3 + c] - pt[3 * s + c]) : 0.0f;
  }

  float a1[3], a2[9], a3[27], a4[81];
#pragma unroll
  for (int i = 0; i < 3; i++) a1[i] = 0.f;
#pragma unroll
  for (int i = 0; i < 9; i++) a2[i] = 0.f;
#pragma unroll
  for (int i = 0; i < 27; i++) a3[i] = 0.f;
#pragma unroll
  for (int i = 0; i < 81; i++) a4[i] = 0.f;

#pragma unroll
  for (int s = 0; s < CHUNK; s++)
    sig_append(a1, a2, a3, a4, dd[3 * s], dd[3 * s + 1], dd[3 * s + 2]);

  // Kogge-Stone suffix Chen product (lane l ends with chunks [l, 63]).
#pragma unroll
  for (int off = 1; off < 64; off <<= 1) {
    const float m = (lane + off < 64) ? 1.0f : 0.0f;  // zero state = identity
    float B1[3], B2[9], B3[27];
#pragma unroll
    for (int i = 0; i < 3; i++) B1[i] = m * __shfl_down(a1[i], off);
#pragma unroll
    for (int i = 0; i < 9; i++) B2[i] = m * __shfl_down(a2[i], off);
#pragma unroll
    for (int i = 0; i < 27; i++) B3[i] = m * __shfl_down(a3[i], off);

#pragma unroll
    for (int e = 0; e < 81; e++) {
      const float b4 = m * __shfl_down(a4[e], off);  // reads pre-update a4[e]
      float v = a4[e] + b4;
      v = fmaf(a3[e / 3], B1[e % 3], v);
      v = fmaf(a2[e / 9], B2[e % 9], v);
      v = fmaf(a1[e / 27], B3[e % 27], v);
      a4[e] = v;
    }
#pragma unroll
    for (int e = 0; e < 27; e++) {
      float v = a3[e] + B3[e];
      v = fmaf(a2[e / 3], B1[e % 3], v);
      v = fmaf(a1[e / 9], B2[e % 9], v);
      a3[e] = v;
    }
#pragma unroll
    for (int e = 0; e < 9; e++) a2[e] = fmaf(a1[e / 3], B1[e % 3], a2[e] + B2[e]);
#pragma unroll
    for (int i = 0; i < 3; i++) a1[i] += B1[i];
  }

  if (lane == 0) {
    float* dst = sig + (size_t)p * SIGC;
#pragma unroll
    for (int i = 0; i < 3; i++) dst[i] = a1[i];
#pragma unroll
    for (int i = 0; i < 9; i++) dst[3 + i] = a2[i];
#pragma unroll
    for (int i = 0; i < 27; i++) dst[12 + i] = a3[i];
#pragma unroll
    for (int i = 0; i < 81; i++) dst[39 + i] = a4[i];
  }
}

// ---------------------------------------------------------------------------
// Kernel 2: h += S @ W1^T.  S:(64,4080), W1:(512,4080), both row-major.
// Grid: 16 j-tiles (32 cols) x 17 K-splits (240). Block = 128 threads;
// each thread owns a 4x4 accumulator: 64 FMA per 8 ds_read_b128.
// K chunked 2x120 to keep LDS at 46.6 KB (stride 124 -> 2-way banks, free).
// ---------------------------------------------------------------------------
__global__ __launch_bounds__(128) void gemm1_kernel(const float* __restrict__ S,
                                                    const float* __restrict__ W1,
                                                    float* __restrict__ h) {
  const int jt = blockIdx.x;   // 0..15 (32 cols each)
  const int ks = blockIdx.y;   // 0..16 (240 k each)
  const int tid = threadIdx.x;
  __shared__ float Ss[64][124];
  __shared__ float Ws[32][124];

  const int ri = tid & 15;     // rows {ri, ri+16, ri+32, ri+48}
  const int cj = tid >> 4;     // cols {4cj .. 4cj+3} within 32-tile
  float acc[4][4];
#pragma unroll
  for (int m = 0; m < 4; m++)
#pragma unroll
    for (int c = 0; c < 4; c++) acc[m][c] = 0.f;

  for (int half = 0; half < 2; half++) {
    const int k0 = ks * 240 + half * 120;
    __syncthreads();
    // stage S tile: 64 rows x 30 float4
    for (int idx = tid; idx < 64 * 30; idx += 128) {
      const int r = idx / 30, q = idx - r * 30;
      const float4 v = *(const float4*)(S + (size_t)r * FAN1 + k0 + q * 4);
      *(float4*)&Ss[r][q * 4] = v;
    }
    // stage W1 tile: 32 rows x 30 float4
    for (int idx = tid; idx < 32 * 30; idx += 128) {
      const int j = idx / 30, q = idx - j * 30;
      const float4 v = *(const float4*)(W1 + (size_t)(jt * 32 + j) * FAN1 + k0 + q * 4);
      *(float4*)&Ws[j][q * 4] = v;
    }
    __syncthreads();

#pragma unroll 2
    for (int kq = 0; kq < 30; kq++) {
      float4 a[4], b[4];
#pragma unroll
      for (int m = 0; m < 4; m++) a[m] = *(const float4*)&Ss[ri + 16 * m][kq * 4];
#pragma unroll
      for (int c = 0; c < 4; c++) b[c] = *(const float4*)&Ws[cj * 4 + c][kq * 4];
#pragma unroll
      for (int m = 0; m < 4; m++)
#pragma unroll
        for (int c = 0; c < 4; c++) {
          acc[m][c] = fmaf(a[m].x, b[c].x, acc[m][c]);
          acc[m][c] = fmaf(a[m].y, b[c].y, acc[m][c]);
          acc[m][c] = fmaf(a[m].z, b[c].z, acc[m][c]);
          acc[m][c] = fmaf(a[m].w, b[c].w, acc[m][c]);
        }
    }
  }

#pragma unroll
  for (int m = 0; m < 4; m++) {
    float* hp = h + (size_t)(ri + 16 * m) * H1 + jt * 32 + cj * 4;
#pragma unroll
    for (int c = 0; c < 4; c++) atomicAdd(hp + c, acc[m][c]);
  }
}

// ---------------------------------------------------------------------------
// Kernel 3: out[b][j] = h[b] . W2[j] + b2[j].  One wave per (b, j).
// ---------------------------------------------------------------------------
__global__ __launch_bounds__(256) void gemm2_kernel(const float* __restrict__ h,
                                                    const float* __restrict__ W2,
                                                    const float* __restrict__ b2,
                                                    float* __restrict__ out) {
  const int b = blockIdx.x;              // 0..63
  const int jg = blockIdx.y;             // 0..38
  const int wave = threadIdx.x >> 6;     // 0..3
  const int lane = threadIdx.x & 63;
  const int j = jg * 4 + wave;
  if (j >= NOUT) return;
  const float* hb = h + b * H1;
  const float* w = W2 + j * H1;
  float acc = 0.f;
#pragma unroll
  for (int i = 0; i < 8; i++) {
    const int k = lane + i * 64;
    acc = fmaf(hb[k], w[k], acc);
  }
#pragma unroll
  for (int off = 32; off > 0; off >>= 1) acc += __shfl_down(acc, off, 64);
  if (lane == 0) out[b * NOUT + j] = acc + b2[j];
}

// ---------------------------------------------------------------------------
extern "C" void kernel_launch(void* const* d_in, const int* in_sizes, int n_in,
                              void* d_out, int out_size, void* d_ws, size_t ws_size,
                              hipStream_t stream) {
  const float* inp = (const float*)d_in[0];  // (64,3,300,17,2)
  const float* W1  = (const float*)d_in[1];  // (512,4080)
  const float* b1  = (const float*)d_in[2];  // (512,)
  const float* W2  = (const float*)d_in[3];  // (155,512)
  const float* b2  = (const float*)d_in[4];  // (155,)
  float* out = (float*)d_out;                // (64,155)

  // ws layout (floats): tp | sig | h   (~8.9 MB total)
  float* tpbuf = (float*)d_ws;                       // 2176*900
  float* sig   = tpbuf + (size_t)NPATH * T_PTS * 3;  // 2176*120
  float* h     = sig + (size_t)NPATH * SIGC;         // 64*512

  transpose_kernel<<<dim3(B_SZ, 4), 256, 0, stream>>>(inp, tpbuf, b1, h);
  sig_kernel<<<NPATH / 4, 256, 0, stream>>>(tpbuf, sig);
  gemm1_kernel<<<dim3(16, 17), 128, 0, stream>>>(sig, W1, h);
  gemm2_kernel<<<dim3(64, 39), 256, 0, stream>>>(h, W2, b2, out);
}

// Round 4
// 138.917 us; speedup vs baseline: 1.2462x; 1.2462x over previous
//
#include <hip/hip_runtime.h>
#include <hip/hip_bf16.h>

// Problem shapes
#define B_SZ 64
#define T_PTS 300
#define N_SEG 299
#define VM 34            // 17*2
#define NPATH (B_SZ*VM)  // 2176
#define SIGC 120         // 3+9+27+81
#define FAN1 4080        // 34*120
#define H1 512
#define NOUT 155
#define GSZ 16           // lanes per path
#define CHUNK 19         // segments per lane (16*19=304 >= 299)
#define TT 75            // transpose t-tile (300/4)

// ---------------------------------------------------------------------------
// Absorb one linear segment with increment (d0,d1,d2) into state a1..a4.
// All array indices compile-time constant -> stays in VGPRs.
// ---------------------------------------------------------------------------
__device__ __forceinline__ void sig_append(float a1[3], float a2[9], float a3[27], float a4[81],
                                           float d0, float d1, float d2) {
  float B1[3] = {d0, d1, d2};
  float Hh[3] = {0.5f * d0, 0.5f * d1, 0.5f * d2};
  float Tt[3] = {(1.0f / 3.0f) * d0, (1.0f / 3.0f) * d1, (1.0f / 3.0f) * d2};
  float Qq[3] = {0.25f * d0, 0.25f * d1, 0.25f * d2};
  float B2[9], B3[27];
#pragma unroll
  for (int i = 0; i < 3; i++)
#pragma unroll
    for (int j = 0; j < 3; j++) B2[i * 3 + j] = B1[i] * Hh[j];
#pragma unroll
  for (int e = 0; e < 27; e++) B3[e] = B2[e / 3] * Tt[e % 3];

#pragma unroll
  for (int e = 0; e < 81; e++) {
    float v = a4[e];
    v = fmaf(B3[e / 3], Qq[e % 3], v);       // + g4[e]
    v = fmaf(a3[e / 3], B1[e % 3], v);       // + a3 (x) g1
    v = fmaf(a2[e / 9], B2[e % 9], v);       // + a2 (x) g2
    v = fmaf(a1[e / 27], B3[e % 27], v);     // + a1 (x) g3
    a4[e] = v;
  }
#pragma unroll
  for (int e = 0; e < 27; e++) {
    float v = a3[e] + B3[e];
    v = fmaf(a2[e / 3], B1[e % 3], v);
    v = fmaf(a1[e / 9], B2[e % 9], v);
    a3[e] = v;
  }
#pragma unroll
  for (int e = 0; e < 9; e++) a2[e] = fmaf(a1[e / 3], B1[e % 3], a2[e] + B2[e]);
  a1[0] += d0; a1[1] += d1; a1[2] += d2;
}

// ---------------------------------------------------------------------------
// Kernel 0: transpose (B,C,T,V,M) -> (P=B*VM, T, C) contiguous paths; fused
// h = broadcast(b1) init (gemm1 accumulates atomically on top).
// ---------------------------------------------------------------------------
__global__ __launch_bounds__(256) void transpose_kernel(const float* __restrict__ inp,
                                                        float* __restrict__ tp,
                                                        const float* __restrict__ b1,
                                                        float* __restrict__ h) {
  const int b = blockIdx.x;       // 0..63
  const int tile = blockIdx.y;    // 0..3
  const int t0 = tile * TT;
  const int tid = threadIdx.x;
  __shared__ float lds[3 * TT * VM];  // 7650 floats = 30.6 KB

  const float* src = inp + (size_t)b * 3 * T_PTS * VM;
  for (int idx = tid; idx < 3 * TT * VM; idx += 256) {
    const int c = idx / (TT * VM);
    const int rem = idx - c * (TT * VM);
    lds[idx] = src[(c * T_PTS + t0) * VM + rem];
  }
  __syncthreads();

  for (int idx = tid; idx < VM * TT * 3; idx += 256) {
    const int vm = idx / (TT * 3);
    const int i = idx - vm * (TT * 3);
    const int tt = i / 3;
    const int c = i - tt * 3;
    tp[((size_t)(b * VM + vm) * T_PTS + t0 + tt) * 3 + c] = lds[(c * TT + tt) * VM + vm];
  }

  if (tile == 0) {
    for (int j = tid; j < H1; j += 256) h[b * H1 + j] = b1[j];
  }
}

// ---------------------------------------------------------------------------
// Kernel 1: signatures. One wave per block; 4 paths per wave (16 lanes each).
// Lane (g,sub) absorbs segments [19*sub, 19*sub+19) of path 4*blk+g with a
// rolling-scalar loop (no register arrays -> no scratch), then a 4-level
// masked __shfl_down Chen combine within the 16-lane group. amdgpu_waves_per_eu(1)
// lets the allocator take ~200 VGPRs without spilling (round-3 failure mode).
// ---------------------------------------------------------------------------
__global__ __launch_bounds__(64)
__attribute__((amdgpu_waves_per_eu(1)))
void sig_kernel(const float* __restrict__ tp, float* __restrict__ sig) {
  const int lane = threadIdx.x & 63;
  const int g = lane >> 4;          // path within wave
  const int sub = lane & (GSZ - 1); // lane within 16-lane group
  const int p = blockIdx.x * 4 + g; // 544*4 = 2176
  const int t0 = sub * CHUNK;

  const float* bp = tp + (size_t)p * (T_PTS * 3) + t0 * 3;

  float a1[3], a2[9], a3[27], a4[81];
#pragma unroll
  for (int i = 0; i < 3; i++) a1[i] = 0.f;
#pragma unroll
  for (int i = 0; i < 9; i++) a2[i] = 0.f;
#pragma unroll
  for (int i = 0; i < 27; i++) a3[i] = 0.f;
#pragma unroll
  for (int i = 0; i < 81; i++) a4[i] = 0.f;

  float x0 = bp[0], x1 = bp[1], x2 = bp[2];
  for (int s = 0; s < CHUNK; s++) {
    // Over-reads (t0+s+1 up to 304) stay inside ws (next path / sig region)
    // and are masked off below. dx=0 is the Chen identity.
    const float y0 = bp[3 * s + 3];
    const float y1 = bp[3 * s + 4];
    const float y2 = bp[3 * s + 5];
    const bool valid = (t0 + s) < N_SEG;
    const float d0 = valid ? (y0 - x0) : 0.0f;
    const float d1 = valid ? (y1 - x1) : 0.0f;
    const float d2 = valid ? (y2 - x2) : 0.0f;
    sig_append(a1, a2, a3, a4, d0, d1, d2);
    x0 = y0; x1 = y1; x2 = y2;
  }

  // Kogge-Stone suffix Chen product within each 16-lane group:
  // after level off, lane sub holds chunks [sub, min(sub+2*off-1, 15)].
#pragma unroll
  for (int off = 1; off < GSZ; off <<= 1) {
    const float m = (sub + off < GSZ) ? 1.0f : 0.0f;  // zero state = identity
    float B1[3], B2[9], B3[27];
#pragma unroll
    for (int i = 0; i < 3; i++) B1[i] = m * __shfl_down(a1[i], off);
#pragma unroll
    for (int i = 0; i < 9; i++) B2[i] = m * __shfl_down(a2[i], off);
#pragma unroll
    for (int i = 0; i < 27; i++) B3[i] = m * __shfl_down(a3[i], off);

#pragma unroll
    for (int e = 0; e < 81; e++) {
      const float b4 = m * __shfl_down(a4[e], off);  // reads pre-update a4[e]
      float v = a4[e] + b4;
      v = fmaf(a3[e / 3], B1[e % 3], v);
      v = fmaf(a2[e / 9], B2[e % 9], v);
      v = fmaf(a1[e / 27], B3[e % 27], v);
      a4[e] = v;
    }
#pragma unroll
    for (int e = 0; e < 27; e++) {
      float v = a3[e] + B3[e];
      v = fmaf(a2[e / 3], B1[e % 3], v);
      v = fmaf(a1[e / 9], B2[e % 9], v);
      a3[e] = v;
    }
#pragma unroll
    for (int e = 0; e < 9; e++) a2[e] = fmaf(a1[e / 3], B1[e % 3], a2[e] + B2[e]);
#pragma unroll
    for (int i = 0; i < 3; i++) a1[i] += B1[i];
  }

  if (sub == 0) {
    float* dst = sig + (size_t)p * SIGC;
#pragma unroll
    for (int i = 0; i < 3; i++) dst[i] = a1[i];
#pragma unroll
    for (int i = 0; i < 9; i++) dst[3 + i] = a2[i];
#pragma unroll
    for (int i = 0; i < 27; i++) dst[12 + i] = a3[i];
#pragma unroll
    for (int i = 0; i < 81; i++) dst[39 + i] = a4[i];
  }
}

// ---------------------------------------------------------------------------
// Kernel 2: h += S @ W1^T.  S:(64,4080) row-major, W1:(512,4080) row-major.
// Grid: (32 j-tiles of 16) x (8 K-splits of 510). LDS-staged, fp32 FMA,
// atomicAdd epilogue (8 adds per element, order-independent).
// (reverted to the round-2 version: best-measured non-sig config)
// ---------------------------------------------------------------------------
__global__ __launch_bounds__(256) void gemm1_kernel(const float* __restrict__ S,
                                                    const float* __restrict__ W1,
                                                    float* __restrict__ h) {
  const int jt = blockIdx.x;   // 0..31
  const int ks = blockIdx.y;   // 0..7
  const int tid = threadIdx.x;
  __shared__ float Ss[64][103];
  __shared__ float Ws[16][103];
  const int k0 = ks * 510;
  const int r = tid >> 2;      // output row (batch)
  const int cq = tid & 3;      // which 4-col group within 16-wide tile
  float acc0 = 0.f, acc1 = 0.f, acc2 = 0.f, acc3 = 0.f;

  for (int kc = 0; kc < 5; kc++) {
    const int kb = k0 + kc * 102;
    __syncthreads();
    for (int idx = tid; idx < 64 * 102; idx += 256) {
      const int rr = idx / 102, kk = idx - rr * 102;
      Ss[rr][kk] = S[rr * FAN1 + kb + kk];
    }
    for (int idx = tid; idx < 16 * 102; idx += 256) {
      const int jj = idx / 102, kk = idx - jj * 102;
      Ws[jj][kk] = W1[(jt * 16 + jj) * FAN1 + kb + kk];
    }
    __syncthreads();
#pragma unroll 6
    for (int k = 0; k < 102; k++) {
      const float a = Ss[r][k];
      acc0 = fmaf(a, Ws[cq * 4 + 0][k], acc0);
      acc1 = fmaf(a, Ws[cq * 4 + 1][k], acc1);
      acc2 = fmaf(a, Ws[cq * 4 + 2][k], acc2);
      acc3 = fmaf(a, Ws[cq * 4 + 3][k], acc3);
    }
  }
  float* hp = h + r * H1 + jt * 16 + cq * 4;
  atomicAdd(hp + 0, acc0);
  atomicAdd(hp + 1, acc1);
  atomicAdd(hp + 2, acc2);
  atomicAdd(hp + 3, acc3);
}

// ---------------------------------------------------------------------------
// Kernel 3: out[b][j] = h[b] . W2[j] + b2[j].  One wave per (b, j).
// ---------------------------------------------------------------------------
__global__ __launch_bounds__(256) void gemm2_kernel(const float* __restrict__ h,
                                                    const float* __restrict__ W2,
                                                    const float* __restrict__ b2,
                                                    float* __restrict__ out) {
  const int b = blockIdx.x;              // 0..63
  const int jg = blockIdx.y;             // 0..38
  const int wave = threadIdx.x >> 6;     // 0..3
  const int lane = threadIdx.x & 63;
  const int j = jg * 4 + wave;
  if (j >= NOUT) return;
  const float* hb = h + b * H1;
  const float* w = W2 + j * H1;
  float acc = 0.f;
#pragma unroll
  for (int i = 0; i < 8; i++) {
    const int k = lane + i * 64;
    acc = fmaf(hb[k], w[k], acc);
  }
#pragma unroll
  for (int off = 32; off > 0; off >>= 1) acc += __shfl_down(acc, off, 64);
  if (lane == 0) out[b * NOUT + j] = acc + b2[j];
}

// ---------------------------------------------------------------------------
extern "C" void kernel_launch(void* const* d_in, const int* in_sizes, int n_in,
                              void* d_out, int out_size, void* d_ws, size_t ws_size,
                              hipStream_t stream) {
  const float* inp = (const float*)d_in[0];  // (64,3,300,17,2)
  const float* W1  = (const float*)d_in[1];  // (512,4080)
  const float* b1  = (const float*)d_in[2];  // (512,)
  const float* W2  = (const float*)d_in[3];  // (155,512)
  const float* b2  = (const float*)d_in[4];  // (155,)
  float* out = (float*)d_out;                // (64,155)

  // ws layout (floats): tp | sig | h   (~8.9 MB total)
  float* tpbuf = (float*)d_ws;                       // 2176*900
  float* sig   = tpbuf + (size_t)NPATH * T_PTS * 3;  // 2176*120
  float* h     = sig + (size_t)NPATH * SIGC;         // 64*512

  transpose_kernel<<<dim3(B_SZ, 4), 256, 0, stream>>>(inp, tpbuf, b1, h);
  sig_kernel<<<NPATH / 4, 64, 0, stream>>>(tpbuf, sig);
  gemm1_kernel<<<dim3(32, 8), 256, 0, stream>>>(sig, W1, h);
  gemm2_kernel<<<dim3(64, 39), 256, 0, stream>>>(h, W2, b2, out);
}

// Round 5
// 137.322 us; speedup vs baseline: 1.2607x; 1.0116x over previous
//
#include <hip/hip_runtime.h>
#include <hip/hip_bf16.h>

// Problem shapes
#define B_SZ 64
#define T_PTS 300
#define N_SEG 299
#define VM 34            // 17*2
#define NPATH (B_SZ*VM)  // 2176
#define SIGC 120         // 3+9+27+81
#define FAN1 4080        // 34*120
#define H1 512
#define NOUT 155
#define GSZ 16           // lanes per path in sig
#define CHUNK 19         // segments per lane (16*19=304 >= 299)
#define TT 75            // transpose t-tile (300/4)

// ---------------------------------------------------------------------------
// Absorb one linear segment with increment (d0,d1,d2) into state a1..a4.
// All array indices compile-time constant -> stays in VGPRs.
// ---------------------------------------------------------------------------
__device__ __forceinline__ void sig_append(float a1[3], float a2[9], float a3[27], float a4[81],
                                           float d0, float d1, float d2) {
  float B1[3] = {d0, d1, d2};
  float Hh[3] = {0.5f * d0, 0.5f * d1, 0.5f * d2};
  float Tt[3] = {(1.0f / 3.0f) * d0, (1.0f / 3.0f) * d1, (1.0f / 3.0f) * d2};
  float Qq[3] = {0.25f * d0, 0.25f * d1, 0.25f * d2};
  float B2[9], B3[27];
#pragma unroll
  for (int i = 0; i < 3; i++)
#pragma unroll
    for (int j = 0; j < 3; j++) B2[i * 3 + j] = B1[i] * Hh[j];
#pragma unroll
  for (int e = 0; e < 27; e++) B3[e] = B2[e / 3] * Tt[e % 3];

#pragma unroll
  for (int e = 0; e < 81; e++) {
    float v = a4[e];
    v = fmaf(B3[e / 3], Qq[e % 3], v);       // + g4[e]
    v = fmaf(a3[e / 3], B1[e % 3], v);       // + a3 (x) g1
    v = fmaf(a2[e / 9], B2[e % 9], v);       // + a2 (x) g2
    v = fmaf(a1[e / 27], B3[e % 27], v);     // + a1 (x) g3
    a4[e] = v;
  }
#pragma unroll
  for (int e = 0; e < 27; e++) {
    float v = a3[e] + B3[e];
    v = fmaf(a2[e / 3], B1[e % 3], v);
    v = fmaf(a1[e / 9], B2[e % 9], v);
    a3[e] = v;
  }
#pragma unroll
  for (int e = 0; e < 9; e++) a2[e] = fmaf(a1[e / 3], B1[e % 3], a2[e] + B2[e]);
  a1[0] += d0; a1[1] += d1; a1[2] += d2;
}

// ---------------------------------------------------------------------------
// Kernel 0: transpose (B,C,T,V,M) -> (P=B*VM, T, C) contiguous paths; fused
// ht = broadcast(b1) init (gemm1 accumulates atomically on top).
// ---------------------------------------------------------------------------
__global__ __launch_bounds__(256) void transpose_kernel(const float* __restrict__ inp,
                                                        float* __restrict__ tp,
                                                        const float* __restrict__ b1,
                                                        float* __restrict__ ht) {
  const int b = blockIdx.x;       // 0..63
  const int tile = blockIdx.y;    // 0..3
  const int t0 = tile * TT;
  const int tid = threadIdx.x;
  __shared__ float lds[3 * TT * VM];  // 7650 floats = 30.6 KB

  const float* src = inp + (size_t)b * 3 * T_PTS * VM;
  for (int idx = tid; idx < 3 * TT * VM; idx += 256) {
    const int c = idx / (TT * VM);
    const int rem = idx - c * (TT * VM);
    lds[idx] = src[(c * T_PTS + t0) * VM + rem];
  }
  __syncthreads();

  for (int idx = tid; idx < VM * TT * 3; idx += 256) {
    const int vm = idx / (TT * 3);
    const int i = idx - vm * (TT * 3);
    const int tt = i / 3;
    const int c = i - tt * 3;
    tp[((size_t)(b * VM + vm) * T_PTS + t0 + tt) * 3 + c] = lds[(c * TT + tt) * VM + vm];
  }

  if (tile == 0) {
    // ht[j][bb] = b1[j] for j in [8b, 8b+8)
    for (int idx = tid; idx < 8 * 64; idx += 256)
      ht[(size_t)(8 * b) * 64 + idx] = b1[8 * b + (idx >> 6)];
  }
}

// ---------------------------------------------------------------------------
// Kernel 1: signatures. One wave per block; 4 paths per wave (16 lanes each).
// Rolling-scalar segment loop (no runtime-indexed register arrays), 4-level
// masked __shfl_down Chen combine. amdgpu_waves_per_eu(1) prevents the
// round-3 spill. Output written TRANSPOSED: St[k][b], k = vm*120 + c.
// ---------------------------------------------------------------------------
__global__ __launch_bounds__(64)
__attribute__((amdgpu_waves_per_eu(1)))
void sig_kernel(const float* __restrict__ tp, float* __restrict__ St) {
  const int lane = threadIdx.x & 63;
  const int g = lane >> 4;          // path within wave
  const int sub = lane & (GSZ - 1); // lane within 16-lane group
  const int p = blockIdx.x * 4 + g; // 544*4 = 2176
  const int t0 = sub * CHUNK;

  const float* bp = tp + (size_t)p * (T_PTS * 3) + t0 * 3;

  float a1[3], a2[9], a3[27], a4[81];
#pragma unroll
  for (int i = 0; i < 3; i++) a1[i] = 0.f;
#pragma unroll
  for (int i = 0; i < 9; i++) a2[i] = 0.f;
#pragma unroll
  for (int i = 0; i < 27; i++) a3[i] = 0.f;
#pragma unroll
  for (int i = 0; i < 81; i++) a4[i] = 0.f;

  float x0 = bp[0], x1 = bp[1], x2 = bp[2];
  for (int s = 0; s < CHUNK; s++) {
    // Over-reads (up to point 304) stay inside ws and are masked off below.
    const float y0 = bp[3 * s + 3];
    const float y1 = bp[3 * s + 4];
    const float y2 = bp[3 * s + 5];
    const bool valid = (t0 + s) < N_SEG;
    const float d0 = valid ? (y0 - x0) : 0.0f;
    const float d1 = valid ? (y1 - x1) : 0.0f;
    const float d2 = valid ? (y2 - x2) : 0.0f;
    sig_append(a1, a2, a3, a4, d0, d1, d2);
    x0 = y0; x1 = y1; x2 = y2;
  }

  // Kogge-Stone suffix Chen product within each 16-lane group.
#pragma unroll
  for (int off = 1; off < GSZ; off <<= 1) {
    const float m = (sub + off < GSZ) ? 1.0f : 0.0f;  // zero state = identity
    float B1[3], B2[9], B3[27];
#pragma unroll
    for (int i = 0; i < 3; i++) B1[i] = m * __shfl_down(a1[i], off);
#pragma unroll
    for (int i = 0; i < 9; i++) B2[i] = m * __shfl_down(a2[i], off);
#pragma unroll
    for (int i = 0; i < 27; i++) B3[i] = m * __shfl_down(a3[i], off);

#pragma unroll
    for (int e = 0; e < 81; e++) {
      const float b4 = m * __shfl_down(a4[e], off);  // reads pre-update a4[e]
      float v = a4[e] + b4;
      v = fmaf(a3[e / 3], B1[e % 3], v);
      v = fmaf(a2[e / 9], B2[e % 9], v);
      v = fmaf(a1[e / 27], B3[e % 27], v);
      a4[e] = v;
    }
#pragma unroll
    for (int e = 0; e < 27; e++) {
      float v = a3[e] + B3[e];
      v = fmaf(a2[e / 3], B1[e % 3], v);
      v = fmaf(a1[e / 9], B2[e % 9], v);
      a3[e] = v;
    }
#pragma unroll
    for (int e = 0; e < 9; e++) a2[e] = fmaf(a1[e / 3], B1[e % 3], a2[e] + B2[e]);
#pragma unroll
    for (int i = 0; i < 3; i++) a1[i] += B1[i];
  }

  if (sub == 0) {
    const int b = p / VM;
    const int vm = p - b * VM;
    float* dst = St + (size_t)(vm * SIGC) * 64 + b;  // St[(vm*120+i)*64 + b]
#pragma unroll
    for (int i = 0; i < 3; i++) dst[(size_t)i * 64] = a1[i];
#pragma unroll
    for (int i = 0; i < 9; i++) dst[(size_t)(3 + i) * 64] = a2[i];
#pragma unroll
    for (int i = 0; i < 27; i++) dst[(size_t)(12 + i) * 64] = a3[i];
#pragma unroll
    for (int i = 0; i < 81; i++) dst[(size_t)(39 + i) * 64] = a4[i];
  }
}

// ---------------------------------------------------------------------------
// Kernel 2: ht[j][b] += sum_k St[k][b] * W1[j][k].  lane = b (M=64=wave!).
// Wave handles 4 j's x 510-k split; St read = 1 coalesced dword/k (L1/L2,
// shared by the block's 4 waves); W1 via SGPR (scalar) loads. No LDS.
// 1024 waves; coalesced atomicAdd epilogue (8 adds/element onto b1 init).
// ---------------------------------------------------------------------------
__global__ __launch_bounds__(256) void gemm1_kernel(const float* __restrict__ St,
                                                    const float* __restrict__ W1,
                                                    float* __restrict__ ht) {
  const int lane = threadIdx.x & 63;
  int wave_id = (blockIdx.x * 256 + threadIdx.x) >> 6;        // 0..1023
  wave_id = __builtin_amdgcn_readfirstlane(wave_id);          // force SGPR
  const int ks = wave_id >> 7;    // 0..7  (k-range of 510)
  const int jg = wave_id & 127;   // 0..127 (4 j's each)

  const float* stp = St + (size_t)(ks * 510) * 64 + lane;
  const float* w1r = W1 + (size_t)(jg * 4) * FAN1 + ks * 510; // uniform -> s_load

  float acc0 = 0.f, acc1 = 0.f, acc2 = 0.f, acc3 = 0.f;
#pragma unroll 6
  for (int k = 0; k < 510; k++) {
    const float sv = stp[(size_t)k * 64];
    acc0 = fmaf(w1r[k], sv, acc0);
    acc1 = fmaf(w1r[FAN1 + k], sv, acc1);
    acc2 = fmaf(w1r[2 * FAN1 + k], sv, acc2);
    acc3 = fmaf(w1r[3 * FAN1 + k], sv, acc3);
  }

  float* hp = ht + (size_t)(jg * 4) * 64 + lane;
  atomicAdd(hp + 0 * 64, acc0);
  atomicAdd(hp + 1 * 64, acc1);
  atomicAdd(hp + 2 * 64, acc2);
  atomicAdd(hp + 3 * 64, acc3);
}

// ---------------------------------------------------------------------------
// Kernel 3: out[b][j] = sum_k2 ht[k2][b] * W2[j][k2] + b2[j].  lane = b.
// Block = one j; 4 waves split k2 (128 each); LDS partial reduce; single
// non-atomic store (no out-init needed).
// ---------------------------------------------------------------------------
__global__ __launch_bounds__(256) void gemm2_kernel(const float* __restrict__ ht,
                                                    const float* __restrict__ W2,
                                                    const float* __restrict__ b2,
                                                    float* __restrict__ out) {
  const int j = blockIdx.x;              // 0..154
  const int lane = threadIdx.x & 63;
  int w = threadIdx.x >> 6;              // 0..3
  w = __builtin_amdgcn_readfirstlane(w);
  __shared__ float red[4][64];

  const float* htp = ht + (size_t)(w * 128) * 64 + lane;
  const float* w2r = W2 + (size_t)j * H1 + w * 128;  // uniform -> s_load
  float acc = 0.f;
#pragma unroll 8
  for (int k = 0; k < 128; k++) acc = fmaf(w2r[k], htp[(size_t)k * 64], acc);

  red[w][lane] = acc;
  __syncthreads();
  if (threadIdx.x < 64) {
    const float tot = red[0][lane] + red[1][lane] + red[2][lane] + red[3][lane];
    out[(size_t)lane * NOUT + j] = tot + b2[j];
  }
}

// ---------------------------------------------------------------------------
extern "C" void kernel_launch(void* const* d_in, const int* in_sizes, int n_in,
                              void* d_out, int out_size, void* d_ws, size_t ws_size,
                              hipStream_t stream) {
  const float* inp = (const float*)d_in[0];  // (64,3,300,17,2)
  const float* W1  = (const float*)d_in[1];  // (512,4080)
  const float* b1  = (const float*)d_in[2];  // (512,)
  const float* W2  = (const float*)d_in[3];  // (155,512)
  const float* b2  = (const float*)d_in[4];  // (155,)
  float* out = (float*)d_out;                // (64,155)

  // ws layout (floats): tp | St | ht   (~9.0 MB total)
  float* tpbuf = (float*)d_ws;                       // 2176*900
  float* St    = tpbuf + (size_t)NPATH * T_PTS * 3;  // 4080*64
  float* ht    = St + (size_t)FAN1 * 64;             // 512*64

  transpose_kernel<<<dim3(B_SZ, 4), 256, 0, stream>>>(inp, tpbuf, b1, ht);
  sig_kernel<<<NPATH / 4, 64, 0, stream>>>(tpbuf, St);
  gemm1_kernel<<<256, 256, 0, stream>>>(St, W1, ht);
  gemm2_kernel<<<NOUT, 256, 0, stream>>>(ht, W2, b2, out);
}

// Round 6
// 119.076 us; speedup vs baseline: 1.4538x; 1.1532x over previous
//
#include <hip/hip_runtime.h>
#include <hip/hip_bf16.h>

// Problem shapes
#define B_SZ 64
#define T_PTS 300
#define N_SEG 299
#define VM 34            // 17*2
#define NPATH (B_SZ*VM)  // 2176
#define SIGC 120         // 3+9+27+81
#define FAN1 4080        // 34*120
#define H1 512
#define NOUT 155
#define GSZ 16           // lanes per path in sig
#define CHUNK 19         // segments per lane (16*19=304 >= 299)
#define TT 75            // transpose t-tile (300/4)
#define KSPL 48          // gemm1 K-splits
#define KW 85            // k per wave (48*85 = 4080)

// ---------------------------------------------------------------------------
// Absorb one linear segment with increment (d0,d1,d2) into state a1..a4.
// All array indices compile-time constant -> stays in VGPRs.
// ---------------------------------------------------------------------------
__device__ __forceinline__ void sig_append(float a1[3], float a2[9], float a3[27], float a4[81],
                                           float d0, float d1, float d2) {
  float B1[3] = {d0, d1, d2};
  float Hh[3] = {0.5f * d0, 0.5f * d1, 0.5f * d2};
  float Tt[3] = {(1.0f / 3.0f) * d0, (1.0f / 3.0f) * d1, (1.0f / 3.0f) * d2};
  float Qq[3] = {0.25f * d0, 0.25f * d1, 0.25f * d2};
  float B2[9], B3[27];
#pragma unroll
  for (int i = 0; i < 3; i++)
#pragma unroll
    for (int j = 0; j < 3; j++) B2[i * 3 + j] = B1[i] * Hh[j];
#pragma unroll
  for (int e = 0; e < 27; e++) B3[e] = B2[e / 3] * Tt[e % 3];

#pragma unroll
  for (int e = 0; e < 81; e++) {
    float v = a4[e];
    v = fmaf(B3[e / 3], Qq[e % 3], v);       // + g4[e]
    v = fmaf(a3[e / 3], B1[e % 3], v);       // + a3 (x) g1
    v = fmaf(a2[e / 9], B2[e % 9], v);       // + a2 (x) g2
    v = fmaf(a1[e / 27], B3[e % 27], v);     // + a1 (x) g3
    a4[e] = v;
  }
#pragma unroll
  for (int e = 0; e < 27; e++) {
    float v = a3[e] + B3[e];
    v = fmaf(a2[e / 3], B1[e % 3], v);
    v = fmaf(a1[e / 9], B2[e % 9], v);
    a3[e] = v;
  }
#pragma unroll
  for (int e = 0; e < 9; e++) a2[e] = fmaf(a1[e / 3], B1[e % 3], a2[e] + B2[e]);
  a1[0] += d0; a1[1] += d1; a1[2] += d2;
}

// ---------------------------------------------------------------------------
// Kernel 0: transpose (B,C,T,V,M) -> (P=B*VM, T, C) contiguous paths; fused
// ht = broadcast(b1) init (gemm1 accumulates atomically on top).
// ---------------------------------------------------------------------------
__global__ __launch_bounds__(256) void transpose_kernel(const float* __restrict__ inp,
                                                        float* __restrict__ tp,
                                                        const float* __restrict__ b1,
                                                        float* __restrict__ ht) {
  const int b = blockIdx.x;       // 0..63
  const int tile = blockIdx.y;    // 0..3
  const int t0 = tile * TT;
  const int tid = threadIdx.x;
  __shared__ float lds[3 * TT * VM];  // 7650 floats = 30.6 KB

  const float* src = inp + (size_t)b * 3 * T_PTS * VM;
  for (int idx = tid; idx < 3 * TT * VM; idx += 256) {
    const int c = idx / (TT * VM);
    const int rem = idx - c * (TT * VM);
    lds[idx] = src[(c * T_PTS + t0) * VM + rem];
  }
  __syncthreads();

  for (int idx = tid; idx < VM * TT * 3; idx += 256) {
    const int vm = idx / (TT * 3);
    const int i = idx - vm * (TT * 3);
    const int tt = i / 3;
    const int c = i - tt * 3;
    tp[((size_t)(b * VM + vm) * T_PTS + t0 + tt) * 3 + c] = lds[(c * TT + tt) * VM + vm];
  }

  if (tile == 0) {
    // ht[j][bb] = b1[j] for j in [8b, 8b+8)
    for (int idx = tid; idx < 8 * 64; idx += 256)
      ht[(size_t)(8 * b) * 64 + idx] = b1[8 * b + (idx >> 6)];
  }
}

// ---------------------------------------------------------------------------
// Kernel 1: signatures. One wave per block; 4 paths per wave (16 lanes each).
// Rolling-scalar segment loop (no runtime-indexed register arrays), 4-level
// masked __shfl_down Chen combine. amdgpu_waves_per_eu(1) prevents the
// round-3 spill. Output written TRANSPOSED: St[k][b], k = vm*120 + c.
// ---------------------------------------------------------------------------
__global__ __launch_bounds__(64)
__attribute__((amdgpu_waves_per_eu(1)))
void sig_kernel(const float* __restrict__ tp, float* __restrict__ St) {
  const int lane = threadIdx.x & 63;
  const int g = lane >> 4;          // path within wave
  const int sub = lane & (GSZ - 1); // lane within 16-lane group
  const int p = blockIdx.x * 4 + g; // 544*4 = 2176
  const int t0 = sub * CHUNK;

  const float* bp = tp + (size_t)p * (T_PTS * 3) + t0 * 3;

  float a1[3], a2[9], a3[27], a4[81];
#pragma unroll
  for (int i = 0; i < 3; i++) a1[i] = 0.f;
#pragma unroll
  for (int i = 0; i < 9; i++) a2[i] = 0.f;
#pragma unroll
  for (int i = 0; i < 27; i++) a3[i] = 0.f;
#pragma unroll
  for (int i = 0; i < 81; i++) a4[i] = 0.f;

  float x0 = bp[0], x1 = bp[1], x2 = bp[2];
  for (int s = 0; s < CHUNK; s++) {
    // Over-reads (up to point 304) stay inside ws and are masked off below.
    const float y0 = bp[3 * s + 3];
    const float y1 = bp[3 * s + 4];
    const float y2 = bp[3 * s + 5];
    const bool valid = (t0 + s) < N_SEG;
    const float d0 = valid ? (y0 - x0) : 0.0f;
    const float d1 = valid ? (y1 - x1) : 0.0f;
    const float d2 = valid ? (y2 - x2) : 0.0f;
    sig_append(a1, a2, a3, a4, d0, d1, d2);
    x0 = y0; x1 = y1; x2 = y2;
  }

  // Kogge-Stone suffix Chen product within each 16-lane group.
#pragma unroll
  for (int off = 1; off < GSZ; off <<= 1) {
    const float m = (sub + off < GSZ) ? 1.0f : 0.0f;  // zero state = identity
    float B1[3], B2[9], B3[27];
#pragma unroll
    for (int i = 0; i < 3; i++) B1[i] = m * __shfl_down(a1[i], off);
#pragma unroll
    for (int i = 0; i < 9; i++) B2[i] = m * __shfl_down(a2[i], off);
#pragma unroll
    for (int i = 0; i < 27; i++) B3[i] = m * __shfl_down(a3[i], off);

#pragma unroll
    for (int e = 0; e < 81; e++) {
      const float b4 = m * __shfl_down(a4[e], off);  // reads pre-update a4[e]
      float v = a4[e] + b4;
      v = fmaf(a3[e / 3], B1[e % 3], v);
      v = fmaf(a2[e / 9], B2[e % 9], v);
      v = fmaf(a1[e / 27], B3[e % 27], v);
      a4[e] = v;
    }
#pragma unroll
    for (int e = 0; e < 27; e++) {
      float v = a3[e] + B3[e];
      v = fmaf(a2[e / 3], B1[e % 3], v);
      v = fmaf(a1[e / 9], B2[e % 9], v);
      a3[e] = v;
    }
#pragma unroll
    for (int e = 0; e < 9; e++) a2[e] = fmaf(a1[e / 3], B1[e % 3], a2[e] + B2[e]);
#pragma unroll
    for (int i = 0; i < 3; i++) a1[i] += B1[i];
  }

  if (sub == 0) {
    const int b = p / VM;
    const int vm = p - b * VM;
    float* dst = St + (size_t)(vm * SIGC) * 64 + b;  // St[(vm*120+i)*64 + b]
#pragma unroll
    for (int i = 0; i < 3; i++) dst[(size_t)i * 64] = a1[i];
#pragma unroll
    for (int i = 0; i < 9; i++) dst[(size_t)(3 + i) * 64] = a2[i];
#pragma unroll
    for (int i = 0; i < 27; i++) dst[(size_t)(12 + i) * 64] = a3[i];
#pragma unroll
    for (int i = 0; i < 81; i++) dst[(size_t)(39 + i) * 64] = a4[i];
  }
}

// ---------------------------------------------------------------------------
// Kernel 2: ht[j][b] += sum_k St[k][b] * W1[j][k].  lane = b (M=64=wave).
// 6144 waves: 48 K-splits (85 k each) x 128 j-groups (4 j each) -> ~4
// waves/SIMD for latency hiding. St chunk fully unrolled into 85 VGPRs
// (static indices, no scratch); W1 rows are wave-uniform streams (scalar
// loads, one SGPR operand per FMA). Coalesced atomicAdd epilogue onto the
// b1-initialized ht (48 adds/element, order-independent).
// ---------------------------------------------------------------------------
__global__ __launch_bounds__(256) void gemm1_kernel(const float* __restrict__ St,
                                                    const float* __restrict__ W1,
                                                    float* __restrict__ ht) {
  const int lane = threadIdx.x & 63;
  int wave_id = (blockIdx.x * 256 + threadIdx.x) >> 6;        // 0..6143
  wave_id = __builtin_amdgcn_readfirstlane(wave_id);          // force SGPR
  const int ks = wave_id / 128;   // 0..47  (k-range of 85)
  const int jg = wave_id & 127;   // 0..127 (4 j's each)
  const int k0 = ks * KW;

  const float* stp = St + (size_t)k0 * 64 + lane;
  const float* w0 = W1 + (size_t)(jg * 4 + 0) * FAN1 + k0;    // uniform -> s_load
  const float* w1 = W1 + (size_t)(jg * 4 + 1) * FAN1 + k0;
  const float* w2 = W1 + (size_t)(jg * 4 + 2) * FAN1 + k0;
  const float* w3 = W1 + (size_t)(jg * 4 + 3) * FAN1 + k0;

  float sv[KW];
#pragma unroll
  for (int i = 0; i < KW; i++) sv[i] = stp[(size_t)i * 64];

  float acc0 = 0.f, acc1 = 0.f, acc2 = 0.f, acc3 = 0.f;
#pragma unroll
  for (int i = 0; i < KW; i++) {
    acc0 = fmaf(sv[i], w0[i], acc0);
    acc1 = fmaf(sv[i], w1[i], acc1);
    acc2 = fmaf(sv[i], w2[i], acc2);
    acc3 = fmaf(sv[i], w3[i], acc3);
  }

  float* hp = ht + (size_t)(jg * 4) * 64 + lane;
  atomicAdd(hp + 0 * 64, acc0);
  atomicAdd(hp + 1 * 64, acc1);
  atomicAdd(hp + 2 * 64, acc2);
  atomicAdd(hp + 3 * 64, acc3);
}

// ---------------------------------------------------------------------------
// Kernel 3: out[b][j] = sum_k2 ht[k2][b] * W2[j][k2] + b2[j].  lane = b.
// Block = one j; 4 waves split k2 (128 each); LDS partial reduce; single
// non-atomic store (no out-init needed).
// ---------------------------------------------------------------------------
__global__ __launch_bounds__(256) void gemm2_kernel(const float* __restrict__ ht,
                                                    const float* __restrict__ W2,
                                                    const float* __restrict__ b2,
                                                    float* __restrict__ out) {
  const int j = blockIdx.x;              // 0..154
  const int lane = threadIdx.x & 63;
  int w = threadIdx.x >> 6;              // 0..3
  w = __builtin_amdgcn_readfirstlane(w);
  __shared__ float red[4][64];

  const float* htp = ht + (size_t)(w * 128) * 64 + lane;
  const float* w2r = W2 + (size_t)j * H1 + w * 128;  // uniform -> s_load
  float acc = 0.f;
#pragma unroll 8
  for (int k = 0; k < 128; k++) acc = fmaf(w2r[k], htp[(size_t)k * 64], acc);

  red[w][lane] = acc;
  __syncthreads();
  if (threadIdx.x < 64) {
    const float tot = red[0][lane] + red[1][lane] + red[2][lane] + red[3][lane];
    out[(size_t)lane * NOUT + j] = tot + b2[j];
  }
}

// ---------------------------------------------------------------------------
extern "C" void kernel_launch(void* const* d_in, const int* in_sizes, int n_in,
                              void* d_out, int out_size, void* d_ws, size_t ws_size,
                              hipStream_t stream) {
  const float* inp = (const float*)d_in[0];  // (64,3,300,17,2)
  const float* W1  = (const float*)d_in[1];  // (512,4080)
  const float* b1  = (const float*)d_in[2];  // (512,)
  const float* W2  = (const float*)d_in[3];  // (155,512)
  const float* b2  = (const float*)d_in[4];  // (155,)
  float* out = (float*)d_out;                // (64,155)

  // ws layout (floats): tp | St | ht   (~9.0 MB total)
  float* tpbuf = (float*)d_ws;                       // 2176*900
  float* St    = tpbuf + (size_t)NPATH * T_PTS * 3;  // 4080*64
  float* ht    = St + (size_t)FAN1 * 64;             // 512*64

  transpose_kernel<<<dim3(B_SZ, 4), 256, 0, stream>>>(inp, tpbuf, b1, ht);
  sig_kernel<<<NPATH / 4, 64, 0, stream>>>(tpbuf, St);
  gemm1_kernel<<<KSPL * 128 / 4, 256, 0, stream>>>(St, W1, ht);
  gemm2_kernel<<<NOUT, 256, 0, stream>>>(ht, W2, b2, out);
}